// Round 1
// 493.087 us; speedup vs baseline: 1.1326x; 1.1326x over previous
//
#include <hip/hip_runtime.h>
#include <hip/hip_bf16.h>
#include <math.h>

// ---------------------------------------------------------------------------
// CRGainHopLayerAnnealed: n=8192, in_dim=256, out_dim=128, d_sub=64, K1=3
// 5-dispatch pipeline:
//   front : Hp = H@Wout^T (+bf16 HpT epi), Z_k = hop_k@W_k^T (+Gram partial
//           epi), P_k = Wout@W_k^T                           [646 blocks]
//   gsum  : Gpart[3][128][4096] -> Gsum[3][4096]             [48 blocks]
//   fused : blocks 0-2 smallk (logdet + Newton-Schulz inv, reads Gsum)
//           blocks 3-514 split-K bf16 MFMA Pbuf[s]=(L@Hp)-partial
//   qtw   : QT_k = s_k * P_k @ Minv_k  (+softmax weights + tail outputs)
//   back  : out = LN(softthresh(Hp + Z@QT^T - 0.15*sum_s Pbuf[s]))
// ---------------------------------------------------------------------------

#define COEFF 0.03125f        // d/(n*eps^2) = 64/(8192*0.25)
#define SCL_LAP (-0.15f)      // -ETA*LAMBDA_LAP

typedef __attribute__((ext_vector_type(8))) short short8;
typedef __attribute__((ext_vector_type(4))) float f32x4;

__device__ __forceinline__ unsigned short f2bf_bits(float f) {
  unsigned int u = __float_as_uint(f);
  unsigned int r = (u + 0x7fffu + ((u >> 16) & 1u)) >> 16;   // RNE
  return (unsigned short)r;
}

// ---- shared 64x64-out fp32 tile GEMM body: C = A (64 rows) * B^T (64 rows)
// BK=16, 256 threads, 4x4 micro. As/Bs are [16][68] k-major slabs.
__device__ __forceinline__ void gemm_body(
    const float* __restrict__ A, const float* __restrict__ B,
    int K, int lda, int ldb, int m0, int n0,
    float* As, float* Bs, float cc[4][4]) {
  const int tid = threadIdx.x;
  const int tx = tid & 15, ty = tid >> 4;
#pragma unroll
  for (int i = 0; i < 4; ++i)
#pragma unroll
    for (int j = 0; j < 4; ++j) cc[i][j] = 0.f;
  const int lr = tid >> 2, lc = (tid & 3) << 2;
  for (int k0 = 0; k0 < K; k0 += 16) {
    float4 av = *(const float4*)(A + (size_t)(m0 + lr) * lda + k0 + lc);
    As[(lc) * 68 + lr] = av.x; As[(lc + 1) * 68 + lr] = av.y;
    As[(lc + 2) * 68 + lr] = av.z; As[(lc + 3) * 68 + lr] = av.w;
    float4 bv = *(const float4*)(B + (size_t)(n0 + lr) * ldb + k0 + lc);
    Bs[(lc) * 68 + lr] = bv.x; Bs[(lc + 1) * 68 + lr] = bv.y;
    Bs[(lc + 2) * 68 + lr] = bv.z; Bs[(lc + 3) * 68 + lr] = bv.w;
    __syncthreads();
#pragma unroll
    for (int kk = 0; kk < 16; ++kk) {
      float4 a4 = *(const float4*)&As[kk * 68 + ty * 4];
      float4 b4 = *(const float4*)&Bs[kk * 68 + tx * 4];
      float a[4] = {a4.x, a4.y, a4.z, a4.w};
      float bb[4] = {b4.x, b4.y, b4.z, b4.w};
#pragma unroll
      for (int i = 0; i < 4; ++i)
#pragma unroll
        for (int j = 0; j < 4; ++j) cc[i][j] = fmaf(a[i], bb[j], cc[i][j]);
    }
    __syncthreads();
  }
}

// ---------------- front: Hp (+HpT), Z (+Gram partial), P ------------------
__global__ __launch_bounds__(256) void front_kernel(
    const float* __restrict__ H, const float* __restrict__ hop,
    const float* __restrict__ Wst, const float* __restrict__ Wout,
    float* __restrict__ Hp, unsigned short* __restrict__ HpT,
    float* __restrict__ Zbuf, float* __restrict__ Gpart,
    float* __restrict__ Pb) {
  __shared__ __align__(16) float smem[4420];
  float* As = smem;
  float* Bs = smem + 1088;
  const int tid = threadIdx.x;
  const int tx = tid & 15, ty = tid >> 4;
  float cc[4][4];
  const int b = blockIdx.x;

  if (b < 256) {
    // -------- Hp = H @ Wout^T, tile (m0,n0); epi: fp32 Hp + bf16 HpT -------
    const int m0 = (b >> 1) * 64, n0 = (b & 1) * 64;
    gemm_body(H, Wout, 256, 256, 256, m0, n0, As, Bs, cc);
#pragma unroll
    for (int i = 0; i < 4; ++i) {
      float4 v = {cc[i][0], cc[i][1], cc[i][2], cc[i][3]};
      *(float4*)(Hp + (size_t)(m0 + ty * 4 + i) * 128 + n0 + tx * 4) = v;
    }
    // stage tile, write transposed bf16: HpT[n][m]
#pragma unroll
    for (int i = 0; i < 4; ++i)
#pragma unroll
      for (int j = 0; j < 4; ++j)
        smem[(ty * 4 + i) * 65 + tx * 4 + j] = cc[i][j];
    __syncthreads();
    const int c = tid >> 2, mb = (tid & 3) << 4;
    __attribute__((aligned(16))) unsigned short tmp[16];
#pragma unroll
    for (int t = 0; t < 16; ++t) tmp[t] = f2bf_bits(smem[(mb + t) * 65 + c]);
    unsigned short* dst = HpT + (size_t)(n0 + c) * 8192 + m0 + mb;
    *(uint4*)dst = *(const uint4*)&tmp[0];
    *(uint4*)(dst + 8) = *(const uint4*)&tmp[8];
  } else if (b < 640) {
    // -------- Z_k chunk (64 rows) = hop_k @ W_k^T; epi: Gram partial -------
    const int i2 = b - 256;
    const int k = i2 >> 7, mblk = i2 & 127;
    const int m0 = mblk * 64;
    gemm_body(hop + (size_t)k * 2097152, Wst + (size_t)k * 16384,
              256, 256, 256, m0, 0, As, Bs, cc);
#pragma unroll
    for (int i = 0; i < 4; ++i) {
      float4 v = {cc[i][0], cc[i][1], cc[i][2], cc[i][3]};
      *(float4*)(Zbuf + (size_t)(m0 + ty * 4 + i) * 192 + k * 64 + tx * 4) = v;
    }
    // Gram partial over the 64 rows this block just produced
#pragma unroll
    for (int i = 0; i < 4; ++i)
#pragma unroll
      for (int j = 0; j < 4; ++j)
        smem[(ty * 4 + i) * 68 + tx * 4 + j] = cc[i][j];
    __syncthreads();
    float g[4][4];
#pragma unroll
    for (int i = 0; i < 4; ++i)
#pragma unroll
      for (int j = 0; j < 4; ++j) g[i][j] = 0.f;
    const int d0 = tx * 4, e0 = ty * 4;
    for (int r = 0; r < 64; ++r) {
      float4 zd4 = *(const float4*)&smem[r * 68 + d0];
      float4 ze4 = *(const float4*)&smem[r * 68 + e0];
      float zd[4] = {zd4.x, zd4.y, zd4.z, zd4.w};
      float ze[4] = {ze4.x, ze4.y, ze4.z, ze4.w};
#pragma unroll
      for (int i = 0; i < 4; ++i)
#pragma unroll
        for (int j = 0; j < 4; ++j) g[i][j] = fmaf(zd[i], ze[j], g[i][j]);
    }
    float* gp = Gpart + ((size_t)k * 128 + mblk) * 4096;
#pragma unroll
    for (int i = 0; i < 4; ++i) {
      float4 v = {g[i][0], g[i][1], g[i][2], g[i][3]};
      *(float4*)(gp + (d0 + i) * 64 + e0) = v;
    }
  } else {
    // -------- P_k = Wout @ W_k^T (128x64), 2 blocks per k ------------------
    const int i2 = b - 640;
    const int k = i2 >> 1;
    const int m0 = (i2 & 1) * 64;
    gemm_body(Wout, Wst + (size_t)k * 16384, 256, 256, 256, m0, 0, As, Bs, cc);
    float* P = Pb + (size_t)k * 8192;
#pragma unroll
    for (int i = 0; i < 4; ++i) {
      float4 v = {cc[i][0], cc[i][1], cc[i][2], cc[i][3]};
      *(float4*)(P + (size_t)(m0 + ty * 4 + i) * 64 + tx * 4) = v;
    }
  }
}

// ---------------- Gsum: reduce 128 Gram partials ---------------------------
__global__ __launch_bounds__(256) void gsum_kernel(
    const float* __restrict__ Gpart, float* __restrict__ Gsum) {
  const int k = blockIdx.x >> 4;
  const int i = ((blockIdx.x & 15) << 8) + threadIdx.x;
  const float* gp = Gpart + (size_t)k * 128 * 4096 + i;
  float s0 = 0.f, s1 = 0.f, s2 = 0.f, s3 = 0.f;
  for (int bb = 0; bb < 128; bb += 4) {
    s0 += gp[(size_t)bb * 4096];
    s1 += gp[(size_t)(bb + 1) * 4096];
    s2 += gp[(size_t)(bb + 2) * 4096];
    s3 += gp[(size_t)(bb + 3) * 4096];
  }
  Gsum[(size_t)k * 4096 + i] = (s0 + s1) + (s2 + s3);
}

// ---------------- fused-dispatch helpers (256 threads) ---------------------
__device__ __forceinline__ float blocksum256(float v, volatile float* scr) {
#pragma unroll
  for (int o = 32; o; o >>= 1) v += __shfl_xor(v, o);
  __syncthreads();
  if ((threadIdx.x & 63) == 0) scr[threadIdx.x >> 6] = v;
  __syncthreads();
  return scr[0] + scr[1] + scr[2] + scr[3];
}

// C = X * Y for 64x64 with X stored k-major (X[kk*64+row]): b128 only.
__device__ __forceinline__ void gemm64s(const float* X, const float* Y,
                                        float acc[4][4]) {
  const int tx = threadIdx.x & 15, ty = threadIdx.x >> 4;
#pragma unroll
  for (int i = 0; i < 4; ++i)
#pragma unroll
    for (int j = 0; j < 4; ++j) acc[i][j] = 0.f;
  for (int kk = 0; kk < 64; ++kk) {
    float4 a4 = *(const float4*)&X[kk * 64 + ty * 4];
    float4 b4 = *(const float4*)&Y[kk * 64 + tx * 4];
    float a[4] = {a4.x, a4.y, a4.z, a4.w};
    float bb[4] = {b4.x, b4.y, b4.z, b4.w};
#pragma unroll
    for (int i = 0; i < 4; ++i)
#pragma unroll
      for (int j = 0; j < 4; ++j) acc[i][j] = fmaf(a[i], bb[j], acc[i][j]);
  }
}

__device__ __forceinline__ void wb64(float* D, const float acc[4][4]) {
  const int tx = threadIdx.x & 15, ty = threadIdx.x >> 4;
#pragma unroll
  for (int i = 0; i < 4; ++i)
#pragma unroll
    for (int j = 0; j < 4; ++j) D[(ty * 4 + i) * 64 + tx * 4 + j] = acc[i][j];
}

__device__ __forceinline__ float dot64(const float* X, const float* Y, float* scr) {
  const int tx = threadIdx.x & 15, ty = threadIdx.x >> 4;
  float v = 0.f;
#pragma unroll
  for (int i = 0; i < 4; ++i)
#pragma unroll
    for (int j = 0; j < 4; ++j) {
      int idx = (ty * 4 + i) * 64 + tx * 4 + j;
      v += X[idx] * Y[idx];
    }
  return blocksum256(v, scr);
}

// ---------------- fused: split-K bf16 MFMA L@Hp  +  smallk -----------------
__global__ __launch_bounds__(256) void fused_big(
    const float* __restrict__ Lp, const unsigned short* __restrict__ HpT,
    float* __restrict__ Pbuf, const float* __restrict__ Gsum,
    float* __restrict__ Minv, float* __restrict__ Rout) {
  __shared__ __align__(16) float smem[12304];
  const int tid = threadIdx.x;

  if (blockIdx.x >= 3) {
    // ---------------- big GEMM path: BM=128,BN=128,BK=32 -------------------
    unsigned short (*As)[40] = (unsigned short(*)[40])smem;          // [128][40]
    unsigned short (*Bs)[40] = (unsigned short(*)[40])(smem + 2560); // [128][40]
    const int g = blockIdx.x - 3;
    const int m0 = (g & 63) * 128;
    const int split = g >> 6;
    const int kbase = split * 1024;
    const int wave = tid >> 6, lane = tid & 63;
    const int ar = tid >> 1, ah = (tid & 1) * 16;
    const size_t lrow = (size_t)(m0 + ar) * 8192;
    const size_t brow = (size_t)ar * 8192;
    f32x4 acc[2][8];
#pragma unroll
    for (int i = 0; i < 2; ++i)
#pragma unroll
      for (int j = 0; j < 8; ++j) acc[i][j] = (f32x4){0.f, 0.f, 0.f, 0.f};
    float4 apf[4];
    uint4 bpf[2];
    {
      const float* ap = Lp + lrow + kbase + ah;
      apf[0] = *(const float4*)(ap); apf[1] = *(const float4*)(ap + 4);
      apf[2] = *(const float4*)(ap + 8); apf[3] = *(const float4*)(ap + 12);
      const unsigned short* bp = HpT + brow + kbase + ah;
      bpf[0] = *(const uint4*)(bp); bpf[1] = *(const uint4*)(bp + 8);
    }
    const int quad = lane >> 4, mcol = lane & 15;
    for (int step = 0; step < 32; ++step) {
      __syncthreads();
      {
        __attribute__((aligned(16))) unsigned short tmp[16];
        const float* f = (const float*)apf;
#pragma unroll
        for (int i = 0; i < 16; ++i) tmp[i] = f2bf_bits(f[i]);
        *(uint4*)&As[ar][ah] = *(const uint4*)&tmp[0];
        *(uint4*)&As[ar][ah + 8] = *(const uint4*)&tmp[8];
        *(uint4*)&Bs[ar][ah] = bpf[0];
        *(uint4*)&Bs[ar][ah + 8] = bpf[1];
      }
      __syncthreads();
      if (step < 31) {  // prefetch next k-tile (overlaps MFMA)
        int kc = kbase + (step + 1) * 32;
        const float* ap = Lp + lrow + kc + ah;
        apf[0] = *(const float4*)(ap); apf[1] = *(const float4*)(ap + 4);
        apf[2] = *(const float4*)(ap + 8); apf[3] = *(const float4*)(ap + 12);
        const unsigned short* bp = HpT + brow + kc + ah;
        bpf[0] = *(const uint4*)(bp); bpf[1] = *(const uint4*)(bp + 8);
      }
      short8 af0 = *(const short8*)&As[wave * 32 + mcol][quad * 8];
      short8 af1 = *(const short8*)&As[wave * 32 + 16 + mcol][quad * 8];
#pragma unroll
      for (int nt = 0; nt < 8; ++nt) {
        short8 bf = *(const short8*)&Bs[nt * 16 + mcol][quad * 8];
        acc[0][nt] = __builtin_amdgcn_mfma_f32_16x16x32_bf16(af0, bf, acc[0][nt], 0, 0, 0);
        acc[1][nt] = __builtin_amdgcn_mfma_f32_16x16x32_bf16(af1, bf, acc[1][nt], 0, 0, 0);
      }
    }
    float* P = Pbuf + (size_t)split * 1048576;
#pragma unroll
    for (int mt = 0; mt < 2; ++mt)
#pragma unroll
      for (int nt = 0; nt < 8; ++nt)
#pragma unroll
        for (int r = 0; r < 4; ++r) {
          int grow = m0 + wave * 32 + mt * 16 + quad * 4 + r;
          int gcol = nt * 16 + mcol;
          P[(size_t)grow * 128 + gcol] = acc[mt][nt][r];
        }
    return;
  }

  // ---------------- smallk path: k = blockIdx.x ----------------------------
  const int k = blockIdx.x;
  float* B0 = smem;          // E
  float* B1 = smem + 4096;   // E2 -> X
  float* B2 = smem + 8192;   // E3 -> T
  float* scr = smem + 12288;
  // M = I + coeff * Gsum[k]
  for (int i = tid; i < 4096; i += 256) {
    B0[i] = COEFF * Gsum[(size_t)k * 4096 + i] + ((i >> 6) == (i & 63) ? 1.f : 0.f);
  }
  __syncthreads();
  // Gershgorin bounds (wave 0; M symmetric, column==row sums)
  if (tid < 64) {
    float rs = 0.f, dg = B0[tid * 65];
    for (int j = 0; j < 64; ++j) rs += fabsf(B0[j * 64 + tid]);
    float lo = 2.f * dg - rs, hi = rs;
#pragma unroll
    for (int o = 32; o; o >>= 1) {
      lo = fminf(lo, __shfl_xor(lo, o));
      hi = fmaxf(hi, __shfl_xor(hi, o));
    }
    if (tid == 0) scr[4] = 0.5f * (fmaxf(lo, 1.f) + hi);
  }
  __syncthreads();
  const float alpha = scr[4], inva = 1.f / alpha;
  for (int i = tid; i < 4096; i += 256) {
    int r = i >> 6, c = i & 63;
    B0[i] = B0[i] * inva - (r == c ? 1.f : 0.f);   // E
  }
  __syncthreads();
  const int tx = tid & 15, ty = tid >> 4;
  float v1 = 0.f, v2 = 0.f;
#pragma unroll
  for (int i = 0; i < 4; ++i)
#pragma unroll
    for (int j = 0; j < 4; ++j) {
      int r = ty * 4 + i, c = tx * 4 + j;
      float e = B0[r * 64 + c];
      if (r == c) v1 += e;
      v2 += e * e;
    }
  float t1 = blocksum256(v1, scr);
  float t2 = blocksum256(v2, scr);
  float acc[4][4];
  gemm64s(B0, B0, acc); __syncthreads(); wb64(B1, acc); __syncthreads();  // E2
  float t3 = dot64(B1, B0, scr);
  float t4 = dot64(B1, B1, scr);
  gemm64s(B1, B0, acc); __syncthreads(); wb64(B2, acc); __syncthreads();  // E3
  float t5 = dot64(B2, B1, scr);
  float t6 = dot64(B2, B2, scr);
  gemm64s(B1, B1, acc);                                                   // E4 (regs)
  {
    float v7 = 0.f, v8 = 0.f;
#pragma unroll
    for (int i = 0; i < 4; ++i)
#pragma unroll
      for (int j = 0; j < 4; ++j) {
        int idx = (ty * 4 + i) * 64 + tx * 4 + j;
        v7 += acc[i][j] * B2[idx];
        v8 += acc[i][j] * acc[i][j];
      }
    float t7 = blocksum256(v7, scr);
    float t8 = blocksum256(v8, scr);
    if (tid == 0) {
      float ld = 64.f * logf(alpha) + t1 - t2 * 0.5f + t3 / 3.f - t4 * 0.25f
                 + t5 * 0.2f - t6 / 6.f + t7 / 7.f - t8 * 0.125f;
      Rout[k] = 0.5f * ld;
    }
  }
  // Newton-Schulz: X0 = I - E ; X <- X(2I - (I+E)X), 2 iters
  for (int i = tid; i < 4096; i += 256) {
    int r = i >> 6, c = i & 63;
    B1[i] = (r == c ? 1.f : 0.f) - B0[i];
  }
  __syncthreads();
  for (int it = 0; it < 2; ++it) {
    gemm64s(B0, B1, acc);       // E*X
    __syncthreads();
    {                           // T = E*X + X -> B2 (own elements)
#pragma unroll
      for (int i = 0; i < 4; ++i)
#pragma unroll
        for (int j = 0; j < 4; ++j) {
          int idx = (ty * 4 + i) * 64 + tx * 4 + j;
          B2[idx] = acc[i][j] + B1[idx];
        }
    }
    __syncthreads();
    gemm64s(B1, B2, acc);       // X*T
    __syncthreads();
    {                           // X = 2X - X*T (own elements)
#pragma unroll
      for (int i = 0; i < 4; ++i)
#pragma unroll
        for (int j = 0; j < 4; ++j) {
          int idx = (ty * 4 + i) * 64 + tx * 4 + j;
          B1[idx] = 2.f * B1[idx] - acc[i][j];
        }
    }
    __syncthreads();
  }
  for (int i = tid; i < 4096; i += 256) Minv[k * 4096 + i] = B1[i] * inva;
}

// ---------------- QT_k = s_k * P_k @ Minv_k  (+ weights + tail) ------------
__global__ __launch_bounds__(256) void qtw_kernel(
    const float* __restrict__ Pb, const float* __restrict__ Minv,
    const float* __restrict__ R, const float* __restrict__ tauP,
    float* __restrict__ QT, float* __restrict__ tail) {
  __shared__ __align__(16) float XT[4096];
  __shared__ __align__(16) float Y[4096];
  __shared__ float wsh;
  const int tid = threadIdx.x;
  const int k = blockIdx.x >> 1;
  const int m0 = (blockIdx.x & 1) * 64;
  if (tid == 0) {
    float R0 = R[0], R1 = R[1], R2 = R[2];
    float d0 = R0, d1 = R1 - R0, d2 = R2 - R1;
    float mean = (d0 + d1 + d2) * (1.f / 3.f);
    float e0 = d0 - mean, e1 = d1 - mean, e2 = d2 - mean;
    float sd = sqrtf((e0 * e0 + e1 * e1 + e2 * e2) * 0.5f) + 1e-6f;
    float n0 = e0 / sd, n1 = e1 / sd, n2 = e2 / sd;
    float tau = tauP[0];
    float x0 = n0 / tau, x1 = n1 / tau, x2 = n2 / tau;
    float mx = fmaxf(x0, fmaxf(x1, x2));
    float w0 = expf(x0 - mx), w1 = expf(x1 - mx), w2 = expf(x2 - mx);
    float s = w0 + w1 + w2;
    w0 /= s; w1 /= s; w2 /= s;
    wsh = 0.015625f * (k == 0 ? w0 : (k == 1 ? w1 : w2));   // ETA*coeff*w_k
    if (blockIdx.x == 0) {
      tail[0] = w0; tail[1] = w1; tail[2] = w2;
      tail[3] = n0; tail[4] = n1; tail[5] = n2;
      tail[6] = d0; tail[7] = d1; tail[8] = d2;
    }
  }
  {
    const int m = tid >> 2, c4 = (tid & 3) << 4;
    const float* src = Pb + (size_t)k * 8192 + (size_t)(m0 + m) * 64 + c4;
#pragma unroll
    for (int t = 0; t < 16; t += 4) {
      float4 v = *(const float4*)(src + t);
      XT[(c4 + t) * 64 + m] = v.x;
      XT[(c4 + t + 1) * 64 + m] = v.y;
      XT[(c4 + t + 2) * 64 + m] = v.z;
      XT[(c4 + t + 3) * 64 + m] = v.w;
    }
    for (int t = tid * 4; t < 4096; t += 1024)
      *(float4*)&Y[t] = *(const float4*)(Minv + (size_t)k * 4096 + t);
  }
  __syncthreads();
  float acc[4][4];
  gemm64s(XT, Y, acc);
  const float s = wsh;
  const int tx = tid & 15, ty = tid >> 4;
#pragma unroll
  for (int i = 0; i < 4; ++i) {
    float4 v = {s * acc[i][0], s * acc[i][1], s * acc[i][2], s * acc[i][3]};
    *(float4*)(QT + (size_t)(m0 + ty * 4 + i) * 192 + k * 64 + tx * 4) = v;
  }
}

// ---- back: pre = Hp + Z@QT^T ; out = LN(softthresh(pre - 0.15*sum Pbuf)) --
// BM=32, BN=128, K=192, grid 256, 256 thr (micro 2x8).
__global__ __launch_bounds__(256) void back_kernel(
    const float* __restrict__ Zbuf, const float* __restrict__ QT,
    const float* __restrict__ Hp, const float* __restrict__ Pbuf,
    const float* __restrict__ thr, const float* __restrict__ gamma,
    const float* __restrict__ beta, float* __restrict__ out) {
  __shared__ __align__(16) float As[16][36];
  __shared__ __align__(16) float Bs[16][132];
  const int tid = threadIdx.x;
  const int tx = tid & 15, ty = tid >> 4;
  const int m0 = blockIdx.x * 32;
  float cc[2][8];
#pragma unroll
  for (int i = 0; i < 2; ++i)
#pragma unroll
    for (int j = 0; j < 8; ++j) cc[i][j] = 0.f;
  const int lr = tid >> 2, lc = (tid & 3) << 2;
  const int jr = tid >> 1, jc = (tid & 1) << 3;
  for (int k0 = 0; k0 < 192; k0 += 16) {
    if (tid < 128) {
      float4 av = *(const float4*)(Zbuf + (size_t)(m0 + lr) * 192 + k0 + lc);
      As[lc][lr] = av.x; As[lc + 1][lr] = av.y;
      As[lc + 2][lr] = av.z; As[lc + 3][lr] = av.w;
    }
    {
      const float* q = QT + (size_t)jr * 192 + k0 + jc;
      float4 b0 = *(const float4*)(q);
      float4 b1 = *(const float4*)(q + 4);
      Bs[jc][jr] = b0.x; Bs[jc + 1][jr] = b0.y;
      Bs[jc + 2][jr] = b0.z; Bs[jc + 3][jr] = b0.w;
      Bs[jc + 4][jr] = b1.x; Bs[jc + 5][jr] = b1.y;
      Bs[jc + 6][jr] = b1.z; Bs[jc + 7][jr] = b1.w;
    }
    __syncthreads();
#pragma unroll
    for (int kk = 0; kk < 16; ++kk) {
      float2 a2 = *(const float2*)&As[kk][ty * 2];
      float4 b4a = *(const float4*)&Bs[kk][tx * 8];
      float4 b4b = *(const float4*)&Bs[kk][tx * 8 + 4];
      float bb[8] = {b4a.x, b4a.y, b4a.z, b4a.w, b4b.x, b4b.y, b4b.z, b4b.w};
#pragma unroll
      for (int j = 0; j < 8; ++j) {
        cc[0][j] = fmaf(a2.x, bb[j], cc[0][j]);
        cc[1][j] = fmaf(a2.y, bb[j], cc[1][j]);
      }
    }
    __syncthreads();
  }
  // epilogue: + Hp + SCL_LAP*sum_s Pbuf -> softthresh -> LN (rows of 128)
  const float4 tA = *(const float4*)(thr + tx * 8);
  const float4 tB = *(const float4*)(thr + tx * 8 + 4);
  const float tv[8] = {fabsf(tA.x), fabsf(tA.y), fabsf(tA.z), fabsf(tA.w),
                       fabsf(tB.x), fabsf(tB.y), fabsf(tB.z), fabsf(tB.w)};
  const float4 gA = *(const float4*)(gamma + tx * 8);
  const float4 gB = *(const float4*)(gamma + tx * 8 + 4);
  const float gv[8] = {gA.x, gA.y, gA.z, gA.w, gB.x, gB.y, gB.z, gB.w};
  const float4 bA = *(const float4*)(beta + tx * 8);
  const float4 bB = *(const float4*)(beta + tx * 8 + 4);
  const float bv[8] = {bA.x, bA.y, bA.z, bA.w, bB.x, bB.y, bB.z, bB.w};
  float sres[2][8], mean[2], inv[2];
#pragma unroll
  for (int i = 0; i < 2; ++i) {
    const size_t off = (size_t)(m0 + ty * 2 + i) * 128 + tx * 8;
    float4 h0 = *(const float4*)(Hp + off);
    float4 h1 = *(const float4*)(Hp + off + 4);
    float p[8] = {0.f, 0.f, 0.f, 0.f, 0.f, 0.f, 0.f, 0.f};
#pragma unroll
    for (int sp = 0; sp < 8; ++sp) {
      const float* pb = Pbuf + (size_t)sp * 1048576 + off;
      float4 q0 = *(const float4*)(pb);
      float4 q1 = *(const float4*)(pb + 4);
      p[0] += q0.x; p[1] += q0.y; p[2] += q0.z; p[3] += q0.w;
      p[4] += q1.x; p[5] += q1.y; p[6] += q1.z; p[7] += q1.w;
    }
    const float hv[8] = {h0.x, h0.y, h0.z, h0.w, h1.x, h1.y, h1.z, h1.w};
    float sum = 0.f;
#pragma unroll
    for (int j = 0; j < 8; ++j) {
      float x = cc[i][j] + hv[j] + SCL_LAP * p[j];
      float a = fmaxf(fabsf(x) - tv[j], 0.f);
      float sx = (x >= 0.f) ? a : -a;
      sres[i][j] = sx;
      sum += sx;
    }
#pragma unroll
    for (int o = 1; o < 16; o <<= 1) sum += __shfl_xor(sum, o);
    mean[i] = sum * (1.f / 128.f);
    float ss = 0.f;
#pragma unroll
    for (int j = 0; j < 8; ++j) {
      float dd = sres[i][j] - mean[i];
      ss += dd * dd;
    }
#pragma unroll
    for (int o = 1; o < 16; o <<= 1) ss += __shfl_xor(ss, o);
    inv[i] = rsqrtf(ss * (1.f / 128.f) + 1e-5f);
  }
#pragma unroll
  for (int i = 0; i < 2; ++i) {
    const size_t off = (size_t)(m0 + ty * 2 + i) * 128 + tx * 8;
    float o8[8];
#pragma unroll
    for (int j = 0; j < 8; ++j)
      o8[j] = (sres[i][j] - mean[i]) * inv[i] * gv[j] + bv[j];
    float4 v0 = {o8[0], o8[1], o8[2], o8[3]};
    float4 v1 = {o8[4], o8[5], o8[6], o8[7]};
    *(float4*)(out + off) = v0;
    *(float4*)(out + off + 4) = v1;
  }
}

// ---------------------------------------------------------------------------
extern "C" void kernel_launch(void* const* d_in, const int* in_sizes, int n_in,
                              void* d_out, int out_size, void* d_ws, size_t ws_size,
                              hipStream_t stream) {
  const float* H = (const float*)d_in[0];
  const float* hop = (const float*)d_in[1];
  const float* L = (const float*)d_in[2];
  const float* Wst = (const float*)d_in[3];
  const float* Wout = (const float*)d_in[4];
  const float* thr = (const float*)d_in[5];
  const float* gamma = (const float*)d_in[6];
  const float* beta = (const float*)d_in[7];
  const float* tau = (const float*)d_in[8];
  float* out = (float*)d_out;

  float* ws = (float*)d_ws;
  float* Zbuf = ws;                       // [8192][192] packed Z (k*64+d)
  float* Hp = Zbuf + 1572864;             // [8192][128]
  float* Gpart = Hp + 1048576;            // [3][128][4096]
  float* Gsum = Gpart + 1572864;          // [3][4096]
  float* Minv = Gsum + 12288;             // [3][64][64]
  float* Rb = Minv + 12288;               // [3]
  float* Pb = Rb + 16;                    // [3][128][64]
  float* QT = Pb + 24576;                 // [128][192] packed QT
  float* Pbuf = QT + 24576;               // [8][8192][128] split-K partials
  unsigned short* HpT = (unsigned short*)(Pbuf + 8388608);  // [128][8192] bf16

  // Hp (+HpT bf16), Z (+Gram partials), P  -- one launch
  front_kernel<<<dim3(646), 256, 0, stream>>>(H, hop, Wst, Wout,
                                              Hp, HpT, Zbuf, Gpart, Pb);
  // reduce Gram partials
  gsum_kernel<<<dim3(48), 256, 0, stream>>>(Gpart, Gsum);
  // fused: smallk (blocks 0-2, reads Gsum) + split-K L@Hp (blocks 3-514)
  fused_big<<<dim3(515), 256, 0, stream>>>(L, HpT, Pbuf, Gsum, Minv, Rb);
  // weights + QT + tail outputs
  qtw_kernel<<<dim3(6), 256, 0, stream>>>(Pb, Minv, Rb, tau, QT, out + 1048576);
  // pre + split-K reduce + soft-threshold + LayerNorm
  back_kernel<<<dim3(256), 256, 0, stream>>>(Zbuf, QT, Hp, Pbuf,
                                             thr, gamma, beta, out);

  (void)in_sizes; (void)n_in; (void)out_size; (void)ws_size;
}